// Round 20
// baseline (98.925 us; speedup 1.0000x reference)
//
#include <hip/hip_runtime.h>

#define NH        32
#define HID       128
#define E_TOT     262144
#define CH_ELEM   8192      // chunk: 8 sl * 1024 elems (indexing unit)
#define NCH_MAIN  16        // 16 * 8 = 128 s-steps
#define TAIL_OFF  131072    // 16 * 8192
#define TAIL_ELEM 8192      // tail chunk: 8 sl (sl 0..4 valid, 5..7 zero)

typedef float        f32x4 __attribute__((ext_vector_type(4)));
typedef short        s16x8 __attribute__((ext_vector_type(8)));
typedef unsigned int u32x4 __attribute__((ext_vector_type(4)));

static __device__ __forceinline__ short f2bf(float f) {
    __bf16 b = (__bf16)f;
    return __builtin_bit_cast(short, b);
}
static __device__ __forceinline__ float selu_f(float x) {
    const float kScale  = 1.0507009873554804934193349852946f;
    const float kAlphaS = 1.7580993408473768599402175208123f; // scale*alpha
    float neg = kAlphaS * (__expf(x) - 1.0f);
    return x > 0.0f ? kScale * x : neg;
}

// ---- pre-kernel: build WT in chunk-linear, LANE-LINEAR order (R8/R15 verbatim).
// main region gid < 131072: bits [c:3][sl:4][it:1][g:2][lrow:4][p:3]
//   kappa = c*512 + sl*32 + g*8 + p   (0..4095)  -> W_A2[kappa>>5][i*32 + (kappa&31)]
// tail region r = gid-131072 < 8192: bits [sl:3][it:1][g:2][lrow:4][p:3]
//   kappa = 4096 + sl*32 + g*8 + p:
//     4096..4127 -> b_A2[i*32 + (kappa-4096)]
//     4128..4255 -> W_b2[kappa-4128][i]
//     else 0
// i = it*16 + lrow in both regions.
__global__ void wt_build(const float* __restrict__ W_A2, const float* __restrict__ b_A2,
                         const float* __restrict__ W_b2, unsigned short* __restrict__ WT) {
    int gid = blockIdx.x * 256 + threadIdx.x;
    if (gid >= TAIL_OFF + TAIL_ELEM) return;
    int it, g, lrow, p, kap;
    if (gid < TAIL_OFF) {
        int c  = gid >> 14;
        int r  = gid & 16383;
        int sl = r >> 10;
        it   = (r >> 9) & 1;
        g    = (r >> 7) & 3;
        lrow = (r >> 3) & 15;
        p    = r & 7;
        kap  = c * 512 + sl * 32 + g * 8 + p;
    } else {
        int r  = gid - TAIL_OFF;
        int sl = r >> 10;
        it   = (r >> 9) & 1;
        g    = (r >> 7) & 3;
        lrow = (r >> 3) & 15;
        p    = r & 7;
        kap  = 4096 + sl * 32 + g * 8 + p;
    }
    int i = it * 16 + lrow;
    float v = 0.0f;
    if (kap < 4096)      v = W_A2[(kap >> 5) * 1024 + i * 32 + (kap & 31)];
    else if (kap < 4128) v = b_A2[i * 32 + (kap - 4096)];
    else if (kap < 4256) v = W_b2[(kap - 4128) * 32 + i];
    WT[gid] = (unsigned short)f2bf(v);
}

// Orientation: D[i_local(row), e_local(col)] per (ct, it) tile.
//   wave = 64 edges (e0 = blk*256 + wid*64)
//   A = W'T slice read DIRECTLY FROM GLOBAL (L2-resident, 272 KB), with an
//       EXPLICIT 1-DEEP SOFTWARE PIPELINE: while computing step sl, the two
//       global_load_dwordx4 for step sl+1 are already in flight (across chunk
//       boundaries too) -> the ~200cyc L2 latency hides under ~220cyc of
//       MFMA+fma compute. This is the only change vs R19 (98us, VGPR=64 had
//       no headroom for the compiler to pipeline on its own).
//   B = h fragment in regs (bf16 once): col-edge = ct*16+lrow, k = g*8+p
__global__ void __launch_bounds__(256, 4)
msg_main(const float* __restrict__ h_i, const float* __restrict__ e_ij,
         const float* __restrict__ W_A1, const float* __restrict__ b_A1,
         const float* __restrict__ W_b1, const float* __restrict__ b_b1,
         const float* __restrict__ b_b2,
         const unsigned short* __restrict__ WT,
         float* __restrict__ out)
{
    __shared__ float cA1[HID], cBA1[HID], cB1a[HID], cB1b[HID], cb2[NH];

    const int tid  = threadIdx.x;
    const int lane = tid & 63;
    const int wid  = tid >> 6;
    const int lrow = lane & 15;
    const int g    = lane >> 4;
    const int e0   = blockIdx.x * 256 + wid * 64;

    if (tid < HID) {
        cA1[tid]  = W_A1[tid];
        cBA1[tid] = b_A1[tid];
        cB1a[tid] = W_b1[tid];
        cB1b[tid] = b_b1[tid];
    }
    if (tid < NH) cb2[tid] = b_b2[tid];

    // lane owns edge e0+lane
    const float ev_own = e_ij[e0 + lane];

    // persistent bf16 h fragments (B operand)
    s16x8 hb[4];
    #pragma unroll
    for (int ct = 0; ct < 4; ++ct) {
        int er = e0 + ct * 16 + lrow;
        const float* hp = h_i + er * 32 + g * 8;
        f32x4 h0 = *(const f32x4*)hp;
        f32x4 h1 = *(const f32x4*)(hp + 4);
        #pragma unroll
        for (int p = 0; p < 4; ++p) {
            hb[ct][p]     = f2bf(h0[p]);
            hb[ct][p + 4] = f2bf(h1[p]);
        }
    }

    // per-col-tile edge scalar (for tail B construction)
    float ev_ct[4];
    #pragma unroll
    for (int ct = 0; ct < 4; ++ct) ev_ct[ct] = __shfl(ev_own, ct * 16 + lrow);

    f32x4 acc[4][2];
    #pragma unroll
    for (int ct = 0; ct < 4; ++ct)
        #pragma unroll
        for (int it = 0; it < 2; ++it)
            acc[ct][it] = (f32x4){0.f, 0.f, 0.f, 0.f};
    const f32x4 zf = (f32x4){0.f, 0.f, 0.f, 0.f};

    float u_own[8];

    __syncthreads();        // consts visible (only barrier in the kernel)

    const unsigned short* wbase = WT + lane * 8;

    // pipeline prologue: A-regs for (c=0, sl=0)
    u32x4 rc0 = *(const u32x4*)(wbase);
    u32x4 rc1 = *(const u32x4*)(wbase + 512);

    for (int c = 0; c < NCH_MAIN; ++c) {
        // u for the 8 s-steps of this chunk (registers, in-wave)
        #pragma unroll
        for (int sl = 0; sl < 8; ++sl) {
            int s = c * 8 + sl;
            u_own[sl] = selu_f(fmaf(ev_own, cA1[s], cBA1[s]));
        }

        #pragma unroll
        for (int sl = 0; sl < 8; ++sl) {
            // issue next step's loads FIRST (sl+1 within chunk; chunk c+1's
            // sl=0 at the boundary — for c=15 that address is TAIL_OFF, valid)
            const unsigned short* wpn = wbase +
                (sl < 7 ? c * CH_ELEM + (sl + 1) * 1024 : (c + 1) * CH_ELEM);
            u32x4 rn0 = *(const u32x4*)(wpn);
            u32x4 rn1 = *(const u32x4*)(wpn + 512);

            s16x8 A0 = __builtin_bit_cast(s16x8, rc0);
            s16x8 A1 = __builtin_bit_cast(s16x8, rc1);
            f32x4 u4[4];
            #pragma unroll
            for (int ct = 0; ct < 4; ++ct) {
                float uv = __shfl(u_own[sl], ct * 16 + lrow);
                u4[ct] = (f32x4){uv, uv, uv, uv};
            }
            // it = 0: 4 MFMAs, then 4 vector fmas
            {
                f32x4 t[4];
                #pragma unroll
                for (int ct = 0; ct < 4; ++ct)
                    t[ct] = __builtin_amdgcn_mfma_f32_16x16x32_bf16(A0, hb[ct], zf, 0, 0, 0);
                #pragma unroll
                for (int ct = 0; ct < 4; ++ct)
                    acc[ct][0] = __builtin_elementwise_fma(t[ct], u4[ct], acc[ct][0]);
            }
            // it = 1
            {
                f32x4 t[4];
                #pragma unroll
                for (int ct = 0; ct < 4; ++ct)
                    t[ct] = __builtin_amdgcn_mfma_f32_16x16x32_bf16(A1, hb[ct], zf, 0, 0, 0);
                #pragma unroll
                for (int ct = 0; ct < 4; ++ct)
                    acc[ct][1] = __builtin_elementwise_fma(t[ct], u4[ct], acc[ct][1]);
            }
            // rotate
            rc0 = rn0;
            rc1 = rn1;
        }
    }

    // ---- tail: sl 0 = b_A2 (pseudo-u = 1, B = h) — rc0/rc1 already hold it
    {
        s16x8 A0 = __builtin_bit_cast(s16x8, rc0);
        s16x8 A1 = __builtin_bit_cast(s16x8, rc1);
        #pragma unroll
        for (int ct = 0; ct < 4; ++ct) {
            acc[ct][0] = __builtin_amdgcn_mfma_f32_16x16x32_bf16(A0, hb[ct], acc[ct][0], 0, 0, 0);
            acc[ct][1] = __builtin_amdgcn_mfma_f32_16x16x32_bf16(A1, hb[ct], acc[ct][1], 0, 0, 0);
        }
    }
    // tail sl 1..4: b-path (A = W_b2 cols, B = selu(e*W_b1 + b_b1))
    #pragma unroll
    for (int q = 0; q < 4; ++q) {
        const unsigned short* wp = wbase + TAIL_OFF + (q + 1) * 1024;
        u32x4 r0 = *(const u32x4*)(wp);
        u32x4 r1 = *(const u32x4*)(wp + 512);
        s16x8 A0 = __builtin_bit_cast(s16x8, r0);
        s16x8 A1 = __builtin_bit_cast(s16x8, r1);
        int tb = q * 32 + g * 8;
        f32x4 wb0 = *(const f32x4*)&cB1a[tb];
        f32x4 wb1 = *(const f32x4*)&cB1a[tb + 4];
        f32x4 bb0 = *(const f32x4*)&cB1b[tb];
        f32x4 bb1 = *(const f32x4*)&cB1b[tb + 4];
        #pragma unroll
        for (int ct = 0; ct < 4; ++ct) {
            s16x8 B;
            #pragma unroll
            for (int p = 0; p < 4; ++p) {
                B[p]     = f2bf(selu_f(fmaf(ev_ct[ct], wb0[p], bb0[p])));
                B[p + 4] = f2bf(selu_f(fmaf(ev_ct[ct], wb1[p], bb1[p])));
            }
            acc[ct][0] = __builtin_amdgcn_mfma_f32_16x16x32_bf16(A0, B, acc[ct][0], 0, 0, 0);
            acc[ct][1] = __builtin_amdgcn_mfma_f32_16x16x32_bf16(A1, B, acc[ct][1], 0, 0, 0);
        }
    }

    // ---- epilogue: add b_b2, store. C/D: col(lane&15)=e_local, row(g*4+r)=i_local
    #pragma unroll
    for (int it = 0; it < 2; ++it) {
        f32x4 b2v = *(const f32x4*)&cb2[it * 16 + g * 4];
        #pragma unroll
        for (int ct = 0; ct < 4; ++ct) {
            int edge = e0 + ct * 16 + lrow;
            f32x4 vo = acc[ct][it] + b2v;
            *(f32x4*)&out[edge * 32 + it * 16 + g * 4] = vo;
        }
    }
}

extern "C" void kernel_launch(void* const* d_in, const int* in_sizes, int n_in,
                              void* d_out, int out_size, void* d_ws, size_t ws_size,
                              hipStream_t stream) {
    const float* h_i  = (const float*)d_in[0];
    const float* e_ij = (const float*)d_in[1];
    const float* W_A1 = (const float*)d_in[2];
    const float* b_A1 = (const float*)d_in[3];
    const float* W_A2 = (const float*)d_in[4];
    const float* b_A2 = (const float*)d_in[5];
    const float* W_b1 = (const float*)d_in[6];
    const float* b_b1 = (const float*)d_in[7];
    const float* W_b2 = (const float*)d_in[8];
    const float* b_b2 = (const float*)d_in[9];

    unsigned short* WT = (unsigned short*)d_ws;   // (131072 + 8192) * 2 = 278,528 B

    wt_build<<<(TAIL_OFF + TAIL_ELEM + 255) / 256, 256, 0, stream>>>(W_A2, b_A2, W_b2, WT);
    msg_main<<<E_TOT / 256, 256, 0, stream>>>(h_i, e_ij, W_A1, b_A1, W_b1, b_b1,
                                              b_b2, WT, (float*)d_out);
}

// Round 21
// 98.696 us; speedup vs baseline: 1.0023x; 1.0023x over previous
//
#include <hip/hip_runtime.h>

#define NH        32
#define HID       128
#define E_TOT     262144
#define CH_ELEM   8192      // chunk: 8 sl * 1024 elems (indexing unit)
#define NCH_MAIN  16        // 16 * 8 = 128 s-steps
#define TAIL_OFF  131072    // 16 * 8192
#define TAIL_ELEM 8192      // tail chunk: 8 sl (sl 0..4 valid, 5..7 zero)

typedef float        f32x4 __attribute__((ext_vector_type(4)));
typedef short        s16x8 __attribute__((ext_vector_type(8)));
typedef unsigned int u32x4 __attribute__((ext_vector_type(4)));

static __device__ __forceinline__ short f2bf(float f) {
    __bf16 b = (__bf16)f;
    return __builtin_bit_cast(short, b);
}
static __device__ __forceinline__ float selu_f(float x) {
    const float kScale  = 1.0507009873554804934193349852946f;
    const float kAlphaS = 1.7580993408473768599402175208123f; // scale*alpha
    float neg = kAlphaS * (__expf(x) - 1.0f);
    return x > 0.0f ? kScale * x : neg;
}

// ---- pre-kernel: build WT in chunk-linear, LANE-LINEAR order (R8/R15 verbatim).
// main region gid < 131072: bits [c:3][sl:4][it:1][g:2][lrow:4][p:3]
//   kappa = c*512 + sl*32 + g*8 + p   (0..4095)  -> W_A2[kappa>>5][i*32 + (kappa&31)]
// tail region r = gid-131072 < 8192: bits [sl:3][it:1][g:2][lrow:4][p:3]
//   kappa = 4096 + sl*32 + g*8 + p:
//     4096..4127 -> b_A2[i*32 + (kappa-4096)]
//     4128..4255 -> W_b2[kappa-4128][i]
//     else 0
// i = it*16 + lrow in both regions.
__global__ void wt_build(const float* __restrict__ W_A2, const float* __restrict__ b_A2,
                         const float* __restrict__ W_b2, unsigned short* __restrict__ WT) {
    int gid = blockIdx.x * 256 + threadIdx.x;
    if (gid >= TAIL_OFF + TAIL_ELEM) return;
    int it, g, lrow, p, kap;
    if (gid < TAIL_OFF) {
        int c  = gid >> 14;
        int r  = gid & 16383;
        int sl = r >> 10;
        it   = (r >> 9) & 1;
        g    = (r >> 7) & 3;
        lrow = (r >> 3) & 15;
        p    = r & 7;
        kap  = c * 512 + sl * 32 + g * 8 + p;
    } else {
        int r  = gid - TAIL_OFF;
        int sl = r >> 10;
        it   = (r >> 9) & 1;
        g    = (r >> 7) & 3;
        lrow = (r >> 3) & 15;
        p    = r & 7;
        kap  = 4096 + sl * 32 + g * 8 + p;
    }
    int i = it * 16 + lrow;
    float v = 0.0f;
    if (kap < 4096)      v = W_A2[(kap >> 5) * 1024 + i * 32 + (kap & 31)];
    else if (kap < 4128) v = b_A2[i * 32 + (kap - 4096)];
    else if (kap < 4256) v = W_b2[(kap - 4128) * 32 + i];
    WT[gid] = (unsigned short)f2bf(v);
}

// Orientation: D[i_local(row), e_local(col)] per (ct, it) tile.
//   wave = 64 edges (e0 = blk*256 + wid*64)
//   A = W'T read DIRECTLY FROM GLOBAL (L2-resident, 272 KB) with FULL-CHUNK
//       REGISTER STAGING: all 16 global_load_dwordx4 of a chunk issue
//       back-to-back into static reg arrays w0[8]/w1[8] (64 VGPRs), then all
//       8 sl compute from registers. One L2-latency exposure per ~1500 cyc of
//       compute instead of per-sl stalls (R19/R20: compiler refused to
//       pipeline 2-deep on its own, VGPR stuck at 60).
//   B = h fragment in regs (bf16 once): col-edge = ct*16+lrow, k = g*8+p
//   launch_bounds (256,3): VGPR cap 170 for ~135 live; 12 waves/CU (R15/16
//   proved 16-vs-32 waves is perf-neutral, so 16->12 is safe).
__global__ void __launch_bounds__(256, 3)
msg_main(const float* __restrict__ h_i, const float* __restrict__ e_ij,
         const float* __restrict__ W_A1, const float* __restrict__ b_A1,
         const float* __restrict__ W_b1, const float* __restrict__ b_b1,
         const float* __restrict__ b_b2,
         const unsigned short* __restrict__ WT,
         float* __restrict__ out)
{
    __shared__ float cA1[HID], cBA1[HID], cB1a[HID], cB1b[HID], cb2[NH];

    const int tid  = threadIdx.x;
    const int lane = tid & 63;
    const int wid  = tid >> 6;
    const int lrow = lane & 15;
    const int g    = lane >> 4;
    const int e0   = blockIdx.x * 256 + wid * 64;

    if (tid < HID) {
        cA1[tid]  = W_A1[tid];
        cBA1[tid] = b_A1[tid];
        cB1a[tid] = W_b1[tid];
        cB1b[tid] = b_b1[tid];
    }
    if (tid < NH) cb2[tid] = b_b2[tid];

    // lane owns edge e0+lane
    const float ev_own = e_ij[e0 + lane];

    // persistent bf16 h fragments (B operand)
    s16x8 hb[4];
    #pragma unroll
    for (int ct = 0; ct < 4; ++ct) {
        int er = e0 + ct * 16 + lrow;
        const float* hp = h_i + er * 32 + g * 8;
        f32x4 h0 = *(const f32x4*)hp;
        f32x4 h1 = *(const f32x4*)(hp + 4);
        #pragma unroll
        for (int p = 0; p < 4; ++p) {
            hb[ct][p]     = f2bf(h0[p]);
            hb[ct][p + 4] = f2bf(h1[p]);
        }
    }

    // per-col-tile edge scalar (for tail B construction)
    float ev_ct[4];
    #pragma unroll
    for (int ct = 0; ct < 4; ++ct) ev_ct[ct] = __shfl(ev_own, ct * 16 + lrow);

    f32x4 acc[4][2];
    #pragma unroll
    for (int ct = 0; ct < 4; ++ct)
        #pragma unroll
        for (int it = 0; it < 2; ++it)
            acc[ct][it] = (f32x4){0.f, 0.f, 0.f, 0.f};
    const f32x4 zf = (f32x4){0.f, 0.f, 0.f, 0.f};

    float u_own[8];

    __syncthreads();        // consts visible (only barrier in the kernel)

    const unsigned short* wbase = WT + lane * 8;

    for (int c = 0; c < NCH_MAIN; ++c) {
        // full-chunk register staging: 16 loads issue back-to-back
        u32x4 w0[8], w1[8];
        #pragma unroll
        for (int sl = 0; sl < 8; ++sl) {
            const unsigned short* wp = wbase + c * CH_ELEM + sl * 1024;
            w0[sl] = *(const u32x4*)(wp);
            w1[sl] = *(const u32x4*)(wp + 512);
        }
        // u for the 8 s-steps (overlaps the load latency)
        #pragma unroll
        for (int sl = 0; sl < 8; ++sl) {
            int s = c * 8 + sl;
            u_own[sl] = selu_f(fmaf(ev_own, cA1[s], cBA1[s]));
        }

        #pragma unroll
        for (int sl = 0; sl < 8; ++sl) {
            s16x8 A0 = __builtin_bit_cast(s16x8, w0[sl]);
            s16x8 A1 = __builtin_bit_cast(s16x8, w1[sl]);
            f32x4 u4[4];
            #pragma unroll
            for (int ct = 0; ct < 4; ++ct) {
                float uv = __shfl(u_own[sl], ct * 16 + lrow);
                u4[ct] = (f32x4){uv, uv, uv, uv};
            }
            // it = 0: 4 MFMAs, then 4 vector fmas
            {
                f32x4 t[4];
                #pragma unroll
                for (int ct = 0; ct < 4; ++ct)
                    t[ct] = __builtin_amdgcn_mfma_f32_16x16x32_bf16(A0, hb[ct], zf, 0, 0, 0);
                #pragma unroll
                for (int ct = 0; ct < 4; ++ct)
                    acc[ct][0] = __builtin_elementwise_fma(t[ct], u4[ct], acc[ct][0]);
            }
            // it = 1
            {
                f32x4 t[4];
                #pragma unroll
                for (int ct = 0; ct < 4; ++ct)
                    t[ct] = __builtin_amdgcn_mfma_f32_16x16x32_bf16(A1, hb[ct], zf, 0, 0, 0);
                #pragma unroll
                for (int ct = 0; ct < 4; ++ct)
                    acc[ct][1] = __builtin_elementwise_fma(t[ct], u4[ct], acc[ct][1]);
            }
        }
    }

    // ---- tail: sl 0 = b_A2 (pseudo-u = 1, B = h)
    {
        const unsigned short* wp = wbase + TAIL_OFF;
        u32x4 r0 = *(const u32x4*)(wp);
        u32x4 r1 = *(const u32x4*)(wp + 512);
        s16x8 A0 = __builtin_bit_cast(s16x8, r0);
        s16x8 A1 = __builtin_bit_cast(s16x8, r1);
        #pragma unroll
        for (int ct = 0; ct < 4; ++ct) {
            acc[ct][0] = __builtin_amdgcn_mfma_f32_16x16x32_bf16(A0, hb[ct], acc[ct][0], 0, 0, 0);
            acc[ct][1] = __builtin_amdgcn_mfma_f32_16x16x32_bf16(A1, hb[ct], acc[ct][1], 0, 0, 0);
        }
    }
    // tail sl 1..4: b-path (A = W_b2 cols, B = selu(e*W_b1 + b_b1))
    #pragma unroll
    for (int q = 0; q < 4; ++q) {
        const unsigned short* wp = wbase + TAIL_OFF + (q + 1) * 1024;
        u32x4 r0 = *(const u32x4*)(wp);
        u32x4 r1 = *(const u32x4*)(wp + 512);
        s16x8 A0 = __builtin_bit_cast(s16x8, r0);
        s16x8 A1 = __builtin_bit_cast(s16x8, r1);
        int tb = q * 32 + g * 8;
        f32x4 wb0 = *(const f32x4*)&cB1a[tb];
        f32x4 wb1 = *(const f32x4*)&cB1a[tb + 4];
        f32x4 bb0 = *(const f32x4*)&cB1b[tb];
        f32x4 bb1 = *(const f32x4*)&cB1b[tb + 4];
        #pragma unroll
        for (int ct = 0; ct < 4; ++ct) {
            s16x8 B;
            #pragma unroll
            for (int p = 0; p < 4; ++p) {
                B[p]     = f2bf(selu_f(fmaf(ev_ct[ct], wb0[p], bb0[p])));
                B[p + 4] = f2bf(selu_f(fmaf(ev_ct[ct], wb1[p], bb1[p])));
            }
            acc[ct][0] = __builtin_amdgcn_mfma_f32_16x16x32_bf16(A0, B, acc[ct][0], 0, 0, 0);
            acc[ct][1] = __builtin_amdgcn_mfma_f32_16x16x32_bf16(A1, B, acc[ct][1], 0, 0, 0);
        }
    }

    // ---- epilogue: add b_b2, store. C/D: col(lane&15)=e_local, row(g*4+r)=i_local
    #pragma unroll
    for (int it = 0; it < 2; ++it) {
        f32x4 b2v = *(const f32x4*)&cb2[it * 16 + g * 4];
        #pragma unroll
        for (int ct = 0; ct < 4; ++ct) {
            int edge = e0 + ct * 16 + lrow;
            f32x4 vo = acc[ct][it] + b2v;
            *(f32x4*)&out[edge * 32 + it * 16 + g * 4] = vo;
        }
    }
}

extern "C" void kernel_launch(void* const* d_in, const int* in_sizes, int n_in,
                              void* d_out, int out_size, void* d_ws, size_t ws_size,
                              hipStream_t stream) {
    const float* h_i  = (const float*)d_in[0];
    const float* e_ij = (const float*)d_in[1];
    const float* W_A1 = (const float*)d_in[2];
    const float* b_A1 = (const float*)d_in[3];
    const float* W_A2 = (const float*)d_in[4];
    const float* b_A2 = (const float*)d_in[5];
    const float* W_b1 = (const float*)d_in[6];
    const float* b_b1 = (const float*)d_in[7];
    const float* W_b2 = (const float*)d_in[8];
    const float* b_b2 = (const float*)d_in[9];

    unsigned short* WT = (unsigned short*)d_ws;   // (131072 + 8192) * 2 = 278,528 B

    wt_build<<<(TAIL_OFF + TAIL_ELEM + 255) / 256, 256, 0, stream>>>(W_A2, b_A2, W_b2, WT);
    msg_main<<<E_TOT / 256, 256, 0, stream>>>(h_i, e_ij, W_A1, b_A1, W_b1, b_b1,
                                              b_b2, WT, (float*)d_out);
}

// Round 22
// 98.349 us; speedup vs baseline: 1.0059x; 1.0035x over previous
//
#include <hip/hip_runtime.h>

#define NH        32
#define HID       128
#define E_TOT     262144
#define CH_ELEM   8192      // chunk: 8 sl * 1024 elems
#define NCH_MAIN  16        // 16 * 8 = 128 s-steps
#define TAIL_OFF  131072    // 16 * 8192
#define TAIL_ELEM 8192      // tail: sl0 = b_A2, sl1..4 = W_b2, sl5..7 zero

typedef float        f32x4  __attribute__((ext_vector_type(4)));
typedef float        f32x16 __attribute__((ext_vector_type(16)));
typedef short        s16x8  __attribute__((ext_vector_type(8)));
typedef unsigned int u32x4  __attribute__((ext_vector_type(4)));

static __device__ __forceinline__ short f2bf(float f) {
    __bf16 b = (__bf16)f;
    return __builtin_bit_cast(short, b);
}
static __device__ __forceinline__ float selu_f(float x) {
    const float kScale  = 1.0507009873554804934193349852946f;
    const float kAlphaS = 1.7580993408473768599402175208123f; // scale*alpha
    float neg = kAlphaS * (__expf(x) - 1.0f);
    return x > 0.0f ? kScale * x : neg;
}

// ---- pre-kernel: build WT for the 32x32x16 A-operand, lane-linear.
// A-layout (32x32x16 bf16): lane l holds A[row = l&31][k = (l>>5)*8 + elem].
// main region gid < 131072: bits [c:4][sl:3][jh:1][l:6][p:3]
//   i = l&31; kappa = c*256 + sl*32 + jh*16 + (l>>5)*8 + p  (0..4095)
//   v = W_A2[kappa>>5][i*32 + (kappa&31)]
// tail region r = gid-131072: bits [sl:3][jh:1][l:6][p:3], i = l&31
//   sl==0 : j = jh*16 + (l>>5)*8 + p        -> b_A2[i*32 + j]
//   sl 1-4: t = (sl-1)*32 + jh*16 + (l>>5)*8 + p -> W_b2[t*32 + i]
//   else 0
__global__ void wt_build(const float* __restrict__ W_A2, const float* __restrict__ b_A2,
                         const float* __restrict__ W_b2, unsigned short* __restrict__ WT) {
    int gid = blockIdx.x * 256 + threadIdx.x;
    if (gid >= TAIL_OFF + TAIL_ELEM) return;
    float v = 0.0f;
    if (gid < TAIL_OFF) {
        int c  = gid >> 13;
        int r  = gid & 8191;
        int sl = r >> 10;
        int jh = (r >> 9) & 1;
        int l  = (r >> 3) & 63;
        int p  = r & 7;
        int i  = l & 31;
        int kap = c * 256 + sl * 32 + jh * 16 + ((l >> 5) << 3) + p;
        v = W_A2[(kap >> 5) * 1024 + i * 32 + (kap & 31)];
    } else {
        int r  = gid - TAIL_OFF;
        int sl = r >> 10;
        int jh = (r >> 9) & 1;
        int l  = (r >> 3) & 63;
        int p  = r & 7;
        int i  = l & 31;
        if (sl == 0) {
            int j = jh * 16 + ((l >> 5) << 3) + p;
            v = b_A2[i * 32 + j];
        } else if (sl <= 4) {
            int t = (sl - 1) * 32 + jh * 16 + ((l >> 5) << 3) + p;
            v = W_b2[t * 32 + i];
        }
    }
    WT[gid] = (unsigned short)f2bf(v);
}

// 32x32x16 restructure. Wave = 64 edges (2 e-tiles of 32) x ALL 32 i.
//   D[i(row), e(col)] per e-tile et: col = lane&31 -> e = e0 + et*32 + (lane&31)
//   A = W'T slice, L2-direct (272 KB, barrier-free): lane l reads 16B at
//       c*CH_ELEM + sl*1024 + jh*512 + l*8  (jh = j-half of the s-block)
//   B = h fragment in regs: lane l holds h[e][j = jh*16 + (l>>5)*8 + elem]
//   per sl: 2 loads + 2 shfl + 4 MFMA (2 independent 2-chains) + 32 fma.
//   MFMA stream 155 -> 129 SIMD-cyc/sl (32x32 = 1015 FLOP/cyc vs 844).
__global__ void __launch_bounds__(256, 3)
msg_main(const float* __restrict__ h_i, const float* __restrict__ e_ij,
         const float* __restrict__ W_A1, const float* __restrict__ b_A1,
         const float* __restrict__ W_b1, const float* __restrict__ b_b1,
         const float* __restrict__ b_b2,
         const unsigned short* __restrict__ WT,
         float* __restrict__ out)
{
    __shared__ float cA1[HID], cBA1[HID], cB1a[HID], cB1b[HID], cb2[NH];

    const int tid  = threadIdx.x;
    const int lane = tid & 63;
    const int wid  = tid >> 6;
    const int el   = lane & 31;        // e_local within e-tile / A row
    const int kh   = lane >> 5;        // k-group (0/1)
    const int e0   = blockIdx.x * 256 + wid * 64;

    if (tid < HID) {
        cA1[tid]  = W_A1[tid];
        cBA1[tid] = b_A1[tid];
        cB1a[tid] = W_b1[tid];
        cB1b[tid] = b_b1[tid];
    }
    if (tid < NH) cb2[tid] = b_b2[tid];

    // lane owns edge e0+lane
    const float ev_own = e_ij[e0 + lane];

    // persistent bf16 h fragments: hb[et][jh], lane holds 8 elems of row er
    s16x8 hb[2][2];
    #pragma unroll
    for (int et = 0; et < 2; ++et) {
        int er = e0 + et * 32 + el;
        #pragma unroll
        for (int jh = 0; jh < 2; ++jh) {
            const float* hp = h_i + er * 32 + jh * 16 + kh * 8;
            f32x4 h0 = *(const f32x4*)hp;
            f32x4 h1 = *(const f32x4*)(hp + 4);
            #pragma unroll
            for (int p = 0; p < 4; ++p) {
                hb[et][jh][p]     = f2bf(h0[p]);
                hb[et][jh][p + 4] = f2bf(h1[p]);
            }
        }
    }

    // per-e-tile edge scalar (tail B construction)
    float ev2[2];
    #pragma unroll
    for (int et = 0; et < 2; ++et) ev2[et] = __shfl(ev_own, et * 32 + el);

    f32x16 acc0, acc1;
    #pragma unroll
    for (int k = 0; k < 16; ++k) { acc0[k] = 0.f; acc1[k] = 0.f; }
    f32x16 zf16;
    #pragma unroll
    for (int k = 0; k < 16; ++k) zf16[k] = 0.f;

    float u_own[8];

    __syncthreads();        // consts visible (only barrier in the kernel)

    const unsigned short* wbase = WT + lane * 8;

    for (int c = 0; c < NCH_MAIN; ++c) {
        #pragma unroll
        for (int sl = 0; sl < 8; ++sl) {
            int s = c * 8 + sl;
            u_own[sl] = selu_f(fmaf(ev_own, cA1[s], cBA1[s]));
        }

        #pragma unroll
        for (int sl = 0; sl < 8; ++sl) {
            const unsigned short* wp = wbase + c * CH_ELEM + sl * 1024;
            u32x4 a0 = *(const u32x4*)(wp);          // jh = 0
            u32x4 a1 = *(const u32x4*)(wp + 512);    // jh = 1
            s16x8 A0 = __builtin_bit_cast(s16x8, a0);
            s16x8 A1 = __builtin_bit_cast(s16x8, a1);
            float uv0 = __shfl(u_own[sl], el);
            float uv1 = __shfl(u_own[sl], 32 + el);
            // two independent 2-chains (jh accumulation), then scale
            f32x16 t0 = __builtin_amdgcn_mfma_f32_32x32x16_bf16(A0, hb[0][0], zf16, 0, 0, 0);
            f32x16 t1 = __builtin_amdgcn_mfma_f32_32x32x16_bf16(A0, hb[1][0], zf16, 0, 0, 0);
            t0 = __builtin_amdgcn_mfma_f32_32x32x16_bf16(A1, hb[0][1], t0, 0, 0, 0);
            t1 = __builtin_amdgcn_mfma_f32_32x32x16_bf16(A1, hb[1][1], t1, 0, 0, 0);
            f32x16 u0, u1;
            #pragma unroll
            for (int k = 0; k < 16; ++k) { u0[k] = uv0; u1[k] = uv1; }
            acc0 = __builtin_elementwise_fma(t0, u0, acc0);
            acc1 = __builtin_elementwise_fma(t1, u1, acc1);
        }
    }

    // ---- tail sl0: b_A2 (pseudo-u = 1, B = h) — accumulate directly
    {
        const unsigned short* wp = wbase + TAIL_OFF;
        u32x4 a0 = *(const u32x4*)(wp);
        u32x4 a1 = *(const u32x4*)(wp + 512);
        s16x8 A0 = __builtin_bit_cast(s16x8, a0);
        s16x8 A1 = __builtin_bit_cast(s16x8, a1);
        acc0 = __builtin_amdgcn_mfma_f32_32x32x16_bf16(A0, hb[0][0], acc0, 0, 0, 0);
        acc1 = __builtin_amdgcn_mfma_f32_32x32x16_bf16(A0, hb[1][0], acc1, 0, 0, 0);
        acc0 = __builtin_amdgcn_mfma_f32_32x32x16_bf16(A1, hb[0][1], acc0, 0, 0, 0);
        acc1 = __builtin_amdgcn_mfma_f32_32x32x16_bf16(A1, hb[1][1], acc1, 0, 0, 0);
    }
    // ---- tail sl1..4: b-path. A = W_b2 cols, B[k][e] = selu(e*W_b1 + b_b1)
    #pragma unroll
    for (int q = 0; q < 4; ++q) {
        const unsigned short* wp = wbase + TAIL_OFF + (q + 1) * 1024;
        u32x4 a0 = *(const u32x4*)(wp);
        u32x4 a1 = *(const u32x4*)(wp + 512);
        s16x8 A0 = __builtin_bit_cast(s16x8, a0);
        s16x8 A1 = __builtin_bit_cast(s16x8, a1);
        #pragma unroll
        for (int jh = 0; jh < 2; ++jh) {
            int tb = q * 32 + jh * 16 + kh * 8;
            f32x4 wb0 = *(const f32x4*)&cB1a[tb];
            f32x4 wb1 = *(const f32x4*)&cB1a[tb + 4];
            f32x4 bb0 = *(const f32x4*)&cB1b[tb];
            f32x4 bb1 = *(const f32x4*)&cB1b[tb + 4];
            s16x8 B0, B1;
            #pragma unroll
            for (int p = 0; p < 4; ++p) {
                B0[p]     = f2bf(selu_f(fmaf(ev2[0], wb0[p], bb0[p])));
                B0[p + 4] = f2bf(selu_f(fmaf(ev2[0], wb1[p], bb1[p])));
                B1[p]     = f2bf(selu_f(fmaf(ev2[1], wb0[p], bb0[p])));
                B1[p + 4] = f2bf(selu_f(fmaf(ev2[1], wb1[p], bb1[p])));
            }
            s16x8 A = jh == 0 ? A0 : A1;
            acc0 = __builtin_amdgcn_mfma_f32_32x32x16_bf16(A, B0, acc0, 0, 0, 0);
            acc1 = __builtin_amdgcn_mfma_f32_32x32x16_bf16(A, B1, acc1, 0, 0, 0);
        }
    }

    // ---- epilogue: add b_b2, store.
    // C/D (m74/m101): col = lane&31 = e_local; row = (reg&3) + 8*(reg>>2) + 4*kh.
    #pragma unroll
    for (int et = 0; et < 2; ++et) {
        int edge = e0 + et * 32 + el;
        const f32x16& a = et == 0 ? acc0 : acc1;
        #pragma unroll
        for (int rq = 0; rq < 4; ++rq) {
            int row0 = rq * 8 + kh * 4;
            f32x4 b2v = *(const f32x4*)&cb2[row0];
            f32x4 vo;
            #pragma unroll
            for (int m = 0; m < 4; ++m) vo[m] = a[rq * 4 + m] + b2v[m];
            *(f32x4*)&out[edge * 32 + row0] = vo;
        }
    }
}

extern "C" void kernel_launch(void* const* d_in, const int* in_sizes, int n_in,
                              void* d_out, int out_size, void* d_ws, size_t ws_size,
                              hipStream_t stream) {
    const float* h_i  = (const float*)d_in[0];
    const float* e_ij = (const float*)d_in[1];
    const float* W_A1 = (const float*)d_in[2];
    const float* b_A1 = (const float*)d_in[3];
    const float* W_A2 = (const float*)d_in[4];
    const float* b_A2 = (const float*)d_in[5];
    const float* W_b1 = (const float*)d_in[6];
    const float* b_b1 = (const float*)d_in[7];
    const float* W_b2 = (const float*)d_in[8];
    const float* b_b2 = (const float*)d_in[9];

    unsigned short* WT = (unsigned short*)d_ws;   // (131072 + 8192) * 2 = 278,528 B

    wt_build<<<(TAIL_OFF + TAIL_ELEM + 255) / 256, 256, 0, stream>>>(W_A2, b_A2, W_b2, WT);
    msg_main<<<E_TOT / 256, 256, 0, stream>>>(h_i, e_ij, W_A1, b_A1, W_b1, b_b1,
                                              b_b2, WT, (float*)d_out);
}